// Round 7
// baseline (123.425 us; speedup 1.0000x reference)
//
#include <hip/hip_runtime.h>

#define NA 512
#define NB 128
#define OUTSTRIDE (3 * NA + 1)   // 1537 floats per batch row

typedef float f32x4 __attribute__((ext_vector_type(4)));

__device__ __forceinline__ void accum(float f, float X, float Y, float Z,
                                      float cix, float ciy, float ciz,
                                      float& fx, float& fy, float& fz, float& ep) {
    float d  = fmaf(f, 200.0f, -100.0f);
    float dx = cix - X;
    float dy = ciy - Y;
    float dz = ciz - Z;
    float r2 = fmaf(dx, dx, fmaf(dy, dy, dz * dz));
    float rinv = (r2 > 0.f) ? rsqrtf(r2) : 0.f;   // diagonal -> 0 (diff==0 there)
    float s = d * rinv;
    fx = fmaf(s, dx, fx);
    fy = fmaf(s, dy, fy);
    fz = fmaf(s, dz, fz);
    ep += s;
}

// Block = 256 threads = 4 waves; block handles batch b, 32 consecutive rows.
// Lane mapping: rh = lane>>5 (row within pair), c = lane&31 (j-position).
// Each wave-load covers 2 rows x 512 B CONTIGUOUS (vs v5's 8 x 128 B) —
// testing whether larger per-instruction segments raise read-path efficiency.
// 4 passes of 2 rows per wave; per-pass 5-step butterfly over c for F.
__global__ __launch_bounds__(256, 8) void eij_main(const float* __restrict__ fe,
                                                   const float* __restrict__ coords,
                                                   float* __restrict__ out,
                                                   float* __restrict__ ws) {
    const int b    = blockIdx.x >> 4;    // 16 row-groups per batch
    const int rg   = blockIdx.x & 15;
    const int w    = threadIdx.x >> 6;
    const int lane = threadIdx.x & 63;
    const int rh   = lane >> 5;
    const int c    = lane & 31;

    __shared__ __align__(16) float s0[NA], s1[NA], s2[NA];  // coords SoA
    __shared__ float sE[4];

    // Stage coords[b] (512 x 3) into SoA LDS.
    const float* cb = coords + (size_t)b * (NA * 3);
    for (int t = threadIdx.x; t < NA * 3; t += 256) {
        int j = t / 3;
        int comp = t - 3 * j;
        float v = cb[t];
        if (comp == 0) s0[j] = v;
        else if (comp == 1) s1[j] = v;
        else s2[j] = v;
    }
    __syncthreads();

    float epAcc = 0.f;

    #pragma unroll
    for (int pass = 0; pass < 4; ++pass) {
        const int i = rg * 32 + pass * 8 + w * 2 + rh;
        const float cix = s0[i], ciy = s1[i], ciz = s2[i];  // 2 addrs, 32-way bcast
        const float* rowbase = fe + ((size_t)(b * NA + i)) * NA;

        float fx = 0.f, fy = 0.f, fz = 0.f, ep = 0.f;
        #pragma unroll
        for (int t4 = 0; t4 < 4; ++t4) {
            const int j0 = t4 * 128 + c * 4;
            const f32x4 f = *(const f32x4*)(rowbase + j0);  // 512 B contig per row
            const f32x4 X = *(const f32x4*)&s0[j0];
            const f32x4 Y = *(const f32x4*)&s1[j0];
            const f32x4 Z = *(const f32x4*)&s2[j0];
            accum(f.x, X.x, Y.x, Z.x, cix, ciy, ciz, fx, fy, fz, ep);
            accum(f.y, X.y, Y.y, Z.y, cix, ciy, ciz, fx, fy, fz, ep);
            accum(f.z, X.z, Y.z, Z.z, cix, ciy, ciz, fx, fy, fz, ep);
            accum(f.w, X.w, Y.w, Z.w, cix, ciy, ciz, fx, fy, fz, ep);
        }

        // Reduce F over the 32 j-positions (lane bits 0-4; halves stay separate).
        #pragma unroll
        for (int off = 1; off <= 16; off <<= 1) {
            fx += __shfl_xor(fx, off);
            fy += __shfl_xor(fy, off);
            fz += __shfl_xor(fz, off);
        }
        if (c == 0) {
            float* ob = out + (size_t)b * OUTSTRIDE + (size_t)i * 3;
            ob[0] = fx;
            ob[1] = fy;
            ob[2] = fz;
        }
        epAcc += ep;
    }

    // E: one full-wave butterfly at the end, then cross-wave via LDS.
    #pragma unroll
    for (int off = 1; off <= 32; off <<= 1)
        epAcc += __shfl_xor(epAcc, off);
    if (lane == 0) sE[w] = epAcc;
    __syncthreads();
    if (threadIdx.x == 0)
        ws[blockIdx.x] = sE[0] + sE[1] + sE[2] + sE[3];
}

// One tiny block: sum the 16 per-block partials per batch, write E.
__global__ void eij_finish(const float* __restrict__ ws, float* __restrict__ out) {
    int b = threadIdx.x;
    if (b < NB) {
        const float* p = ws + b * 16;
        float e = 0.f;
        #pragma unroll
        for (int k = 0; k < 16; ++k) e += p[k];
        out[(size_t)b * OUTSTRIDE + 3 * NA] = 0.5f * e;
    }
}

extern "C" void kernel_launch(void* const* d_in, const int* in_sizes, int n_in,
                              void* d_out, int out_size, void* d_ws, size_t ws_size,
                              hipStream_t stream) {
    const float* fe     = (const float*)d_in[0];
    const float* coords = (const float*)d_in[1];
    float* out          = (float*)d_out;
    float* ws           = (float*)d_ws;

    hipLaunchKernelGGL(eij_main, dim3(NB * 16), dim3(256), 0, stream, fe, coords, out, ws);
    hipLaunchKernelGGL(eij_finish, dim3(1), dim3(128), 0, stream, ws, out);
}

// Round 8
// 31.130 us; speedup vs baseline: 3.9648x; 3.9648x over previous
//
#include <hip/hip_runtime.h>

#define NA 512
#define NB 128
#define OUTSTRIDE (3 * NA + 1)   // 1537 floats per batch row

__device__ __forceinline__ void accum(float f, float X, float Y, float Z,
                                      float cix, float ciy, float ciz,
                                      float& fx, float& fy, float& fz, float& ep) {
    float d  = fmaf(f, 200.0f, -100.0f);
    float dx = cix - X;
    float dy = ciy - Y;
    float dz = ciz - Z;
    float r2 = fmaf(dx, dx, fmaf(dy, dy, dz * dz));
    float rinv = (r2 > 0.f) ? rsqrtf(r2) : 0.f;   // diagonal -> 0 (diff==0 there)
    float s = d * rinv;
    fx = fmaf(s, dx, fx);
    fy = fmaf(s, dy, fy);
    fz = fmaf(s, dz, fz);
    ep += s;
}

// v5 structure (measured 31.0 us — best of 7 variants):
// Block = 256 threads = 4 waves; block handles batch b, 32 consecutive rows.
// Wave w owns 8 rows. lane: r = lane>>3 (row), c = lane&7 (position).
// Load t4: lane reads float4 at j = t4*32 + c*4 -> 8 lanes = 128 B dense
// contiguous per row (full sectors), rows 2 KB apart. Coords: conflict-free
// broadcast b128 from LDS SoA (8 lanes cover all 32 banks exactly once, the
// other 56 lanes broadcast). Reduction: 3-step butterfly over c only.
__global__ __launch_bounds__(256, 8) void eij_main(const float* __restrict__ fe,
                                                   const float* __restrict__ coords,
                                                   float* __restrict__ out,
                                                   float* __restrict__ ws) {
    const int b    = blockIdx.x >> 4;    // 16 row-groups per batch
    const int rg   = blockIdx.x & 15;
    const int w    = threadIdx.x >> 6;
    const int lane = threadIdx.x & 63;
    const int r    = lane >> 3;
    const int c    = lane & 7;

    __shared__ __align__(16) float s0[NA], s1[NA], s2[NA];  // coords SoA
    __shared__ float sE[4];

    // Stage coords[b] (512 x 3) into SoA LDS.
    const float* cb = coords + (size_t)b * (NA * 3);
    for (int t = threadIdx.x; t < NA * 3; t += 256) {
        int j = t / 3;
        int comp = t - 3 * j;
        float v = cb[t];
        if (comp == 0) s0[j] = v;
        else if (comp == 1) s1[j] = v;
        else s2[j] = v;
    }
    __syncthreads();

    const int i = rg * 32 + w * 8 + r;
    const float cix = s0[i], ciy = s1[i], ciz = s2[i];   // 8 addrs, 8-way broadcast

    const float4* rowp = (const float4*)(fe + ((size_t)(b * NA + i)) * NA) + c;

    float fx = 0.f, fy = 0.f, fz = 0.f, ep = 0.f;
    #pragma unroll
    for (int t4 = 0; t4 < 16; ++t4) {
        const float4 f = rowp[8 * t4];            // dense: 8 lanes = 128 B
        const int j0 = t4 * 32 + c * 4;
        const float4 X = *(const float4*)&s0[j0]; // banks c*4..c*4+3 -> all 32
        const float4 Y = *(const float4*)&s1[j0];
        const float4 Z = *(const float4*)&s2[j0];
        accum(f.x, X.x, Y.x, Z.x, cix, ciy, ciz, fx, fy, fz, ep);
        accum(f.y, X.y, Y.y, Z.y, cix, ciy, ciz, fx, fy, fz, ep);
        accum(f.z, X.z, Y.z, Z.z, cix, ciy, ciz, fx, fy, fz, ep);
        accum(f.w, X.w, Y.w, Z.w, cix, ciy, ciz, fx, fy, fz, ep);
    }

    // Reduce F over the 8 within-row positions (lane bits 0-2).
    #pragma unroll
    for (int off = 1; off <= 4; off <<= 1) {
        fx += __shfl_xor(fx, off);
        fy += __shfl_xor(fy, off);
        fz += __shfl_xor(fz, off);
        ep += __shfl_xor(ep, off);
    }

    if (c == 0) {
        float* ob = out + (size_t)b * OUTSTRIDE + (size_t)i * 3;
        ob[0] = fx;
        ob[1] = fy;
        ob[2] = fz;
    }

    // Finish E: reduce across rows (bits 3-5), then across waves via LDS.
    #pragma unroll
    for (int off = 8; off <= 32; off <<= 1)
        ep += __shfl_xor(ep, off);
    if (lane == 0) sE[w] = ep;
    __syncthreads();
    if (threadIdx.x == 0)
        ws[blockIdx.x] = sE[0] + sE[1] + sE[2] + sE[3];
}

// One tiny block: sum the 16 per-block partials per batch, write E.
__global__ void eij_finish(const float* __restrict__ ws, float* __restrict__ out) {
    int b = threadIdx.x;
    if (b < NB) {
        const float* p = ws + b * 16;
        float e = 0.f;
        #pragma unroll
        for (int k = 0; k < 16; ++k) e += p[k];
        out[(size_t)b * OUTSTRIDE + 3 * NA] = 0.5f * e;
    }
}

extern "C" void kernel_launch(void* const* d_in, const int* in_sizes, int n_in,
                              void* d_out, int out_size, void* d_ws, size_t ws_size,
                              hipStream_t stream) {
    const float* fe     = (const float*)d_in[0];
    const float* coords = (const float*)d_in[1];
    float* out          = (float*)d_out;
    float* ws           = (float*)d_ws;

    hipLaunchKernelGGL(eij_main, dim3(NB * 16), dim3(256), 0, stream, fe, coords, out, ws);
    hipLaunchKernelGGL(eij_finish, dim3(1), dim3(128), 0, stream, ws, out);
}